// Round 10
// baseline (1659.630 us; speedup 1.0000x reference)
//
#include <hip/hip_runtime.h>

typedef unsigned short u16;
typedef unsigned int   u32;
typedef __attribute__((ext_vector_type(8))) short short8;
typedef __attribute__((ext_vector_type(4))) float f32x4;

#define DD      768
#define KK      6144   /* 8*768 : [root | W0..W6] concatenated on K */
#define NREL    7
#define NLAYERS 5

__device__ __forceinline__ float b2f(u16 v) {
  return __uint_as_float(((u32)v) << 16);
}
__device__ __forceinline__ u16 f2bf(float f) {
  u32 x = __float_as_uint(f);
  x += 0x7fffu + ((x >> 16) & 1u);
  return (u16)(x >> 16);
}
__device__ __forceinline__ void gload16(const void* g, void* l) {
  __builtin_amdgcn_global_load_lds(
      (const __attribute__((address_space(1))) void*)g,
      (__attribute__((address_space(3))) void*)l, 16, 0, 0);
}

// ---------- setup kernels ----------

__global__ void cast_x_kernel(const float* __restrict__ x, u16* __restrict__ H, size_t n) {
  for (size_t i = ((size_t)blockIdx.x * 256 + threadIdx.x) * 4; i < n; i += (size_t)gridDim.x * 256 * 4) {
    float4 v = *(const float4*)&x[i];
    u32 lo = (u32)f2bf(v.x) | ((u32)f2bf(v.y) << 16);
    u32 hi = (u32)f2bf(v.z) | ((u32)f2bf(v.w) << 16);
    uint2 o; o.x = lo; o.y = hi;
    *(uint2*)&H[i] = o;
  }
}

__global__ void count_kernel(const int* __restrict__ eidx, const int* __restrict__ etype,
                             int* cnt_dst, int* cnt_rel, int E, int Nn) {
  int e = blockIdx.x * 256 + threadIdx.x;
  if (e >= E) return;
  int dst = eidx[E + e];
  int rel = etype[e] + 1;
  atomicAdd(&cnt_dst[dst], 1);
  atomicAdd(&cnt_rel[(size_t)rel * Nn + dst], 1);
}

__global__ __launch_bounds__(1024) void scan_kernel(const int* __restrict__ cnt, int* __restrict__ offs, int n) {
  __shared__ int part[1024];
  int t = threadIdx.x;
  int per = (n + 1023) / 1024;
  int base = t * per;
  int s = 0;
  for (int i = 0; i < per; ++i) { int idx = base + i; if (idx < n) s += cnt[idx]; }
  part[t] = s;
  __syncthreads();
  for (int o = 1; o < 1024; o <<= 1) {
    int v = (t >= o) ? part[t - o] : 0;
    __syncthreads();
    part[t] += v;
    __syncthreads();
  }
  int excl = (t == 0) ? 0 : part[t - 1];
  s = excl;
  for (int i = 0; i < per; ++i) { int idx = base + i; if (idx < n) { offs[idx] = s; s += cnt[idx]; } }
  if (t == 1023) offs[n] = part[1023];
}

__global__ void fillperm_kernel(const int* __restrict__ eidx, const int* __restrict__ offs,
                                int* fill, int* perm, int E) {
  int e = blockIdx.x * 256 + threadIdx.x;
  if (e >= E) return;
  int dst = eidx[E + e];
  int pos = offs[dst] + atomicAdd(&fill[dst], 1);
  perm[pos] = e;
}

// Per-layer weight conversion into MFMA-native fragment-major layout (validated R7):
// Bn u16 index = ((n>>4)*192 + kkblk)*512 + ((kq*16 + (n&15))*8 + e
__global__ void wcat_kernel(const float* __restrict__ W, const float* __restrict__ R, u16* __restrict__ Bn) {
  __shared__ float t[32 * 33];
  int b = blockIdx.x;
  int s = b / 576, rem = b % 576;
  int kt = rem / 24, nt = rem % 24;
  const float* src = (s == 0) ? R : (W + (size_t)(s - 1) * DD * DD);
  int tj = threadIdx.x & 31, ti = threadIdx.x >> 5;  // ti 0..7
#pragma unroll
  for (int i = 0; i < 4; ++i) {
    int kk = kt * 32 + ti + i * 8;
    t[(ti + i * 8) * 33 + tj] = src[(size_t)kk * DD + nt * 32 + tj];
  }
  __syncthreads();
  int kkidx = s * 24 + kt;            // 32-wide K block index 0..191
  int kq = tj >> 3, e = tj & 7;
#pragma unroll
  for (int i = 0; i < 4; ++i) {
    int n = nt * 32 + ti + i * 8;
    size_t idx = ((size_t)(n >> 4) * 192 + kkidx) * 512 + (size_t)(kq * 16 + (n & 15)) * 8 + e;
    Bn[idx] = f2bf(t[tj * 33 + ti + i * 8]);
  }
}

// One block (192 thr) per destination node; per-thread register accumulation;
// fused own-row copy into segment 0. A stays row-major (Acat).
__global__ __launch_bounds__(192) void aggregate_kernel(
    const u16* __restrict__ H, const int* __restrict__ esrc, const int* __restrict__ etype,
    const int* __restrict__ offs, const int* __restrict__ perm, const int* __restrict__ cnt_rel,
    u16* __restrict__ Acat, int node0, int Nn) {
  int v = node0 + blockIdx.x;
  int t = threadIdx.x;
  int j0 = t * 4;  // 192*4 = 768
  size_t rowbase = (size_t)blockIdx.x * KK;
  *(uint2*)&Acat[rowbase + j0] = *(const uint2*)&H[(size_t)v * DD + j0];
  float a0[4] = {0,0,0,0}, a1[4] = {0,0,0,0}, a2[4] = {0,0,0,0}, a3[4] = {0,0,0,0};
  float a4[4] = {0,0,0,0}, a5[4] = {0,0,0,0}, a6[4] = {0,0,0,0};
  int beg = offs[v], end = offs[v + 1];
  for (int e = beg; e < end; ++e) {
    int eid = perm[e];
    int src = esrc[eid];
    int rel = etype[eid] + 1;
    uint2 w = *(const uint2*)&H[(size_t)src * DD + j0];
    float f0 = b2f((u16)(w.x & 0xffff));
    float f1 = b2f((u16)(w.x >> 16));
    float f2 = b2f((u16)(w.y & 0xffff));
    float f3 = b2f((u16)(w.y >> 16));
    switch (rel) {
      case 0: a0[0]+=f0; a0[1]+=f1; a0[2]+=f2; a0[3]+=f3; break;
      case 1: a1[0]+=f0; a1[1]+=f1; a1[2]+=f2; a1[3]+=f3; break;
      case 2: a2[0]+=f0; a2[1]+=f1; a2[2]+=f2; a2[3]+=f3; break;
      case 3: a3[0]+=f0; a3[1]+=f1; a3[2]+=f2; a3[3]+=f3; break;
      case 4: a4[0]+=f0; a4[1]+=f1; a4[2]+=f2; a4[3]+=f3; break;
      case 5: a5[0]+=f0; a5[1]+=f1; a5[2]+=f2; a5[3]+=f3; break;
      default: a6[0]+=f0; a6[1]+=f1; a6[2]+=f2; a6[3]+=f3; break;
    }
  }
  const float* regs[NREL] = {a0, a1, a2, a3, a4, a5, a6};
#pragma unroll
  for (int r = 0; r < NREL; ++r) {
    int c = cnt_rel[(size_t)r * Nn + v];
    float inv = (c > 0) ? 1.f / (float)c : 0.f;
    const float* a = regs[r];
    u32 lo = (u32)f2bf(a[0] * inv) | ((u32)f2bf(a[1] * inv) << 16);
    u32 hi = (u32)f2bf(a[2] * inv) | ((u32)f2bf(a[3] * inv) << 16);
    uint2 o; o.x = lo; o.y = hi;
    *(uint2*)&Acat[rowbase + (size_t)(r + 1) * DD + j0] = o;
  }
}

// ---------- hybrid GEMM: A via LDS (4 slots, BK=32, swizzled), B direct
// global->reg from L2-resident fragment-major Bn. Halves LDS-out traffic
// (the measured 85 B/cyc pipe limit) so LDS 768 cyc < MFMA 1030 cyc per step.

#define MFMA_(a_, b_, c_) __builtin_amdgcn_mfma_f32_16x16x32_bf16(a_, b_, c_, 0, 0, 0)
#define BAR   __builtin_amdgcn_s_barrier()
#define VM6   asm volatile("s_waitcnt vmcnt(6)" ::: "memory")
#define VM4   asm volatile("s_waitcnt vmcnt(4)" ::: "memory")
#define VM0   asm volatile("s_waitcnt vmcnt(0)" ::: "memory")

__global__ __launch_bounds__(512, 1) void gemmhy_kernel(
    const u16* __restrict__ A, const u16* __restrict__ Bn, const float* __restrict__ bias,
    u16* __restrict__ Hout, float* __restrict__ Cout, int Mvalid, int Mtiles) {
  // A slots: 4 x (256 rows x 32 k x 2B) = 64 KB
  __shared__ char smA[4][16384];

  int tid = threadIdx.x;
  int lane = tid & 63;
  int wv = tid >> 6;               // 0..7
  int wm = wv >> 2, wn = wv & 3;   // wave = 128 rows x 64 cols

  // XCD-bijective swizzle (m204); bm-fastest => same-XCD blocks share bn (B L2 slice ~3.1MB)
  int nwg = Mtiles * 3;
  int orig = (int)blockIdx.x;
  int q8 = nwg >> 3, r8 = nwg & 7;
  int xcd = orig & 7, rank = orig >> 3;
  int wg = (xcd < r8 ? xcd * (q8 + 1) : r8 * (q8 + 1) + (xcd - r8) * q8) + rank;
  int bm = wg % Mtiles, bn = wg / Mtiles;

  // A staging: linear LDS dest, inverse-swizzled global source (64B rows, 4 chunks).
  // thread t -> row t>>2 (+128j), chunk t&3; source chunk = (t&3)^((t>>3)&3).
  int sch = (tid & 3) ^ ((tid >> 3) & 3);
  const char* gA[2];
#pragma unroll
  for (int j = 0; j < 2; ++j) {
    int ra = bm * 256 + j * 128 + (tid >> 2);
    if (ra > Mvalid - 1) ra = Mvalid - 1;
    gA[j] = (const char*)A + (size_t)ra * (KK * 2) + sch * 16;
  }
  // swizzled ds_read lane offset: rsel*64 + ((kq ^ ((rsel>>1)&3))*16), + wave m-offset
  int rsel = lane & 15, kq = lane >> 4;
  int loff = rsel * 64 + ((kq ^ ((rsel >> 1) & 3)) * 16) + wm * 8192;

  // B fragment pointers (fragment-major Bn; 1KB per (ntile,kblk) frag)
  const char* pb[4];
#pragma unroll
  for (int n = 0; n < 4; ++n)
    pb[n] = (const char*)Bn + ((size_t)(bn * 16 + wn * 4 + n) * 192) * 1024 + lane * 16;

  f32x4 acc[8][4];
#pragma unroll
  for (int m = 0; m < 8; ++m)
#pragma unroll
    for (int n = 0; n < 4; ++n) acc[m][n] = (f32x4){0.f, 0.f, 0.f, 0.f};

#define STAGE(T2, SL)                                                     \
  do {                                                                    \
    size_t ko_ = (size_t)(T2) * 64;                                       \
    gload16(gA[0] + ko_, &smA[SL][tid * 16]);                             \
    gload16(gA[1] + ko_, &smA[SL][8192 + tid * 16]);                      \
  } while (0)

#define LOADB(T2, BR)                                                     \
  do {                                                                    \
    size_t bo_ = (size_t)(T2) * 1024;                                     \
    BR[0] = *(const short8*)(pb[0] + bo_);                                \
    BR[1] = *(const short8*)(pb[1] + bo_);                                \
    BR[2] = *(const short8*)(pb[2] + bo_);                                \
    BR[3] = *(const short8*)(pb[3] + bo_);                                \
  } while (0)

// step T: barrier; ds_read A(T) from slot SL; stage A(T+2); load B(T+1)->NXTB;
// vmcnt (retires A(T+1) stage + B(T) regs); 32 MFMA with aF x CURB.
#define KSTEP(T, SL, CURB, NXTB, DO_STG, DO_BLD, VMW)                     \
  do {                                                                    \
    BAR;                                                                  \
    short8 aF[8];                                                         \
    _Pragma("unroll")                                                     \
    for (int m_ = 0; m_ < 8; ++m_)                                        \
      aF[m_] = *(const short8*)(&smA[SL][m_ * 1024 + loff]);              \
    if (DO_STG) STAGE((T) + 2, ((SL) + 2) & 3);                           \
    if (DO_BLD) LOADB((T) + 1, NXTB);                                     \
    VMW;                                                                  \
    __builtin_amdgcn_s_setprio(1);                                        \
    _Pragma("unroll")                                                     \
    for (int m_ = 0; m_ < 8; ++m_)                                        \
      _Pragma("unroll")                                                   \
      for (int n_ = 0; n_ < 4; ++n_)                                      \
        acc[m_][n_] = MFMA_(aF[m_], CURB[n_], acc[m_][n_]);               \
    __builtin_amdgcn_s_setprio(0);                                        \
  } while (0)

  short8 bE[4], bO[4];

  // prologue: stage A(0),A(1); load B(0); retire A(0); barrier comes in KSTEP
  STAGE(0, 0);
  STAGE(1, 1);
  LOADB(0, bE);
  VM6;

  for (int t = 0; t < 188; t += 4) {
    KSTEP(t + 0, 0, bE, bO, 1, 1, VM6);
    KSTEP(t + 1, 1, bO, bE, 1, 1, VM6);
    KSTEP(t + 2, 2, bE, bO, 1, 1, VM6);
    KSTEP(t + 3, 3, bO, bE, 1, 1, VM6);
  }
  KSTEP(188, 0, bE, bO, 1, 1, VM6);   // stages A(190), loads B(189)
  KSTEP(189, 1, bO, bE, 1, 1, VM6);   // stages A(191), loads B(190)
  KSTEP(190, 2, bE, bO, 0, 1, VM4);   // loads B(191); retire A(191)+B(190)
  KSTEP(191, 3, bO, bE, 0, 0, VM0);   // drain

#undef KSTEP
#undef LOADB
#undef STAGE

  // ---- epilogue: bias + ReLU, write bf16 h_next / f32 out ----
  int rif = (lane >> 4) * 4;
  int cidx = lane & 15;
#pragma unroll
  for (int m = 0; m < 8; ++m) {
    int rl = bm * 256 + wm * 128 + m * 16 + rif;
#pragma unroll
    for (int n = 0; n < 4; ++n) {
      int c = bn * 256 + wn * 64 + n * 16 + cidx;
      float bv = bias[c];
#pragma unroll
      for (int j = 0; j < 4; ++j) {
        int r = rl + j;
        if (r < Mvalid) {
          float v = acc[m][n][j] + bv;
          v = v > 0.f ? v : 0.f;
          if (Hout) Hout[(size_t)r * DD + c] = f2bf(v);
          if (Cout) Cout[(size_t)r * DD + c] = v;
        }
      }
    }
  }
}

// ---------- host ----------

static inline size_t alignup(size_t x, size_t a) { return (x + a - 1) & ~(a - 1); }

extern "C" void kernel_launch(void* const* d_in, const int* in_sizes, int n_in,
                              void* d_out, int out_size, void* d_ws, size_t ws_size,
                              hipStream_t stream) {
  const float* x       = (const float*)d_in[0];
  const int*   eidx    = (const int*)d_in[1];
  const int*   etype   = (const int*)d_in[2];
  const float* weights = (const float*)d_in[3];
  const float* roots   = (const float*)d_in[4];
  const float* biases  = (const float*)d_in[5];
  float* out = (float*)d_out;

  const int Nn = in_sizes[0] / DD;  // 20000
  const int E  = in_sizes[2];       // 100000

  char* p = (char*)d_ws;
  size_t off = 0;
  auto carve = [&](size_t bytes) -> char* {
    char* r = p + off;
    off = alignup(off + bytes, 256);
    return r;
  };
  u16* H0      = (u16*)carve((size_t)Nn * DD * 2);
  u16* Bn      = (u16*)carve((size_t)DD * KK * 2);
  int* cnt_rel = (int*)carve((size_t)NREL * Nn * 4);
  int* cnt_dst = (int*)carve((size_t)Nn * 4);
  int* offs    = (int*)carve((size_t)(Nn + 1) * 4);
  int* fill    = (int*)carve((size_t)Nn * 4);
  int* perm    = (int*)carve((size_t)E * 4);

  size_t rem = (ws_size > off) ? (ws_size - off) : 0;
  int McCap = (int)(rem / ((size_t)KK * 2));
  int Mpad = ((Nn + 255) / 256) * 256;
  int Mc = (McCap < Mpad) ? (McCap & ~255) : Mpad;
  if (Mc < 256) return;  // workspace too small — fail visibly rather than corrupt
  u16* Acat = (u16*)(p + off);
  int nchunks = (Nn + Mc - 1) / Mc;
  u16* H1 = (u16*)d_out;  // bf16 ping buffer inside d_out

  (void)hipMemsetAsync(cnt_rel, 0, (size_t)NREL * Nn * 4, stream);
  (void)hipMemsetAsync(cnt_dst, 0, (size_t)Nn * 4, stream);
  (void)hipMemsetAsync(fill, 0, (size_t)Nn * 4, stream);

  int eg = (E + 255) / 256;
  count_kernel<<<eg, 256, 0, stream>>>(eidx, etype, cnt_dst, cnt_rel, E, Nn);
  scan_kernel<<<1, 1024, 0, stream>>>(cnt_dst, offs, Nn);
  fillperm_kernel<<<eg, 256, 0, stream>>>(eidx, offs, fill, perm, E);
  cast_x_kernel<<<2048, 256, 0, stream>>>(x, H0, (size_t)Nn * DD);

  const u16* Hin = H0;
  u16* Hnext = H1;
  for (int l = 0; l < NLAYERS; ++l) {
    wcat_kernel<<<8 * 576, 256, 0, stream>>>(weights + (size_t)l * NREL * DD * DD,
                                             roots + (size_t)l * DD * DD, Bn);
    for (int c = 0; c < nchunks; ++c) {
      int node0 = c * Mc;
      int nn = (Nn - node0 < Mc) ? (Nn - node0) : Mc;
      aggregate_kernel<<<nn, 192, 0, stream>>>(Hin, eidx, etype, offs, perm, cnt_rel,
                                               Acat, node0, Nn);
      int mt = (nn + 255) / 256;
      u16* ho = (l < NLAYERS - 1) ? (Hnext + (size_t)node0 * DD) : nullptr;
      float* co = (l == NLAYERS - 1) ? (out + (size_t)node0 * DD) : nullptr;
      gemmhy_kernel<<<mt * 3, 512, 0, stream>>>(Acat, Bn, biases + (size_t)l * DD, ho, co, nn, mt);
    }
    const u16* t_ = Hin;
    Hin = Hnext;
    Hnext = (u16*)t_;
  }
}

// Round 12
// 1489.109 us; speedup vs baseline: 1.1145x; 1.1145x over previous
//
#include <hip/hip_runtime.h>

typedef unsigned short u16;
typedef unsigned int   u32;
typedef unsigned long long u64;
typedef __attribute__((ext_vector_type(8))) short short8;
typedef __attribute__((ext_vector_type(4))) float f32x4;

#define DD      768
#define KK      6144   /* 8*768 : [root | W0..W6] concatenated on K */
#define NREL    7
#define NLAYERS 5

__device__ __forceinline__ float b2f(u16 v) {
  return __uint_as_float(((u32)v) << 16);
}
__device__ __forceinline__ u16 f2bf(float f) {
  u32 x = __float_as_uint(f);
  x += 0x7fffu + ((x >> 16) & 1u);
  return (u16)(x >> 16);
}
__device__ __forceinline__ void gload16(const void* g, void* l) {
  __builtin_amdgcn_global_load_lds(
      (const __attribute__((address_space(1))) void*)g,
      (__attribute__((address_space(3))) void*)l, 16, 0, 0);
}

// ---------- setup kernels ----------

__global__ void cast_x_kernel(const float* __restrict__ x, u16* __restrict__ H, size_t n) {
  for (size_t i = ((size_t)blockIdx.x * 256 + threadIdx.x) * 4; i < n; i += (size_t)gridDim.x * 256 * 4) {
    float4 v = *(const float4*)&x[i];
    u32 lo = (u32)f2bf(v.x) | ((u32)f2bf(v.y) << 16);
    u32 hi = (u32)f2bf(v.z) | ((u32)f2bf(v.w) << 16);
    uint2 o; o.x = lo; o.y = hi;
    *(uint2*)&H[i] = o;
  }
}

// cnt_rel row convention: row r ∈ [0,6] == relation r == A_cat segment r+1.
__global__ void count_kernel(const int* __restrict__ eidx, const int* __restrict__ etype,
                             int* cnt_dst, int* cnt_rel, int E, int Nn) {
  int e = blockIdx.x * 256 + threadIdx.x;
  if (e >= E) return;
  int dst = eidx[E + e];
  int rel = etype[e] + 1;   // 0..6
  atomicAdd(&cnt_dst[dst], 1);
  atomicAdd(&cnt_rel[(size_t)rel * Nn + dst], 1);
}

__global__ __launch_bounds__(1024) void scan_kernel(const int* __restrict__ cnt, int* __restrict__ offs, int n) {
  __shared__ int part[1024];
  int t = threadIdx.x;
  int per = (n + 1023) / 1024;
  int base = t * per;
  int s = 0;
  for (int i = 0; i < per; ++i) { int idx = base + i; if (idx < n) s += cnt[idx]; }
  part[t] = s;
  __syncthreads();
  for (int o = 1; o < 1024; o <<= 1) {
    int v = (t >= o) ? part[t - o] : 0;
    __syncthreads();
    part[t] += v;
    __syncthreads();
  }
  int excl = (t == 0) ? 0 : part[t - 1];
  s = excl;
  for (int i = 0; i < per; ++i) { int idx = base + i; if (idx < n) { offs[idx] = s; s += cnt[idx]; } }
  if (t == 1023) offs[n] = part[1023];
}

__global__ void fillperm_kernel(const int* __restrict__ eidx, const int* __restrict__ offs,
                                int* fill, int* perm, int E) {
  int e = blockIdx.x * 256 + threadIdx.x;
  if (e >= E) return;
  int dst = eidx[E + e];
  int pos = offs[dst] + atomicAdd(&fill[dst], 1);
  perm[pos] = e;
}

// per-node 7-bit relation mask: bit r <=> relation r present (row r of cnt_rel)
__global__ void nodemask_kernel(const int* __restrict__ cnt_rel, int* __restrict__ mask,
                                int* __restrict__ mh, int Nn) {
  int v = blockIdx.x * 256 + threadIdx.x;
  if (v >= Nn) return;
  int m = 0;
#pragma unroll
  for (int r = 0; r < NREL; ++r)
    m |= (cnt_rel[(size_t)r * Nn + v] > 0) ? (1 << r) : 0;
  mask[v] = m;
  atomicAdd(&mh[m], 1);
}

__global__ void mscan_kernel(const int* __restrict__ mh, int* __restrict__ mb) {
  int t = threadIdx.x;  // 128 threads
  int acc = 0;
  for (int i = 0; i < t; ++i) acc += mh[i];
  mb[t] = acc;
}

__global__ void mscatter_kernel(const int* __restrict__ mask, const int* __restrict__ mb,
                                int* __restrict__ mf, int* __restrict__ prow, int Nn) {
  int v = blockIdx.x * 256 + threadIdx.x;
  if (v >= Nn) return;
  int m = mask[v];
  int pos = mb[m] + atomicAdd(&mf[m], 1);
  prow[pos] = v;
}

// per 256-row tile: union mask -> packed ascending segment list (seg0 always first);
// bit r of mask => segment r+1 present.
__global__ void tilemask_kernel(const int* __restrict__ prow, const int* __restrict__ mask,
                                u64* __restrict__ packs, int* __restrict__ pcnts, int Nn) {
  __shared__ int u;
  int t = threadIdx.x;
  if (t == 0) u = 0;
  __syncthreads();
  int idx = blockIdx.x * 256 + t;
  int m = (idx < Nn) ? mask[prow[idx]] : 0;
  atomicOr(&u, m);
  __syncthreads();
  if (t == 0) {
    int mm = u;
    u64 pk = 0;       // byte 0 = segment 0 (root), value 0
    int cnt = 1;
    for (int r = 0; r < NREL; ++r)
      if (mm & (1 << r)) { pk |= ((u64)(r + 1)) << (8 * cnt); ++cnt; }
    packs[blockIdx.x] = pk;
    pcnts[blockIdx.x] = cnt;
  }
}

// Per-layer weight conversion: Bt[n][seg*768+kk] = bf16( seg==0 ? roots[kk][n] : W[seg-1][kk][n] )
__global__ void wcat_kernel(const float* __restrict__ W, const float* __restrict__ R, u16* __restrict__ Bt) {
  __shared__ float t[32 * 33];
  int b = blockIdx.x;
  int s = b / 576, rem = b % 576;
  int kt = rem / 24, nt = rem % 24;
  const float* src = (s == 0) ? R : (W + (size_t)(s - 1) * DD * DD);
  int tj = threadIdx.x & 31, ti = threadIdx.x >> 5;  // ti 0..7
#pragma unroll
  for (int i = 0; i < 4; ++i) {
    int kk = kt * 32 + ti + i * 8;
    t[(ti + i * 8) * 33 + tj] = src[(size_t)kk * DD + nt * 32 + tj];
  }
  __syncthreads();
#pragma unroll
  for (int i = 0; i < 4; ++i) {
    int nn_ = nt * 32 + ti + i * 8;
    Bt[(size_t)nn_ * KK + (size_t)s * DD + kt * 32 + tj] = f2bf(t[tj * 33 + ti + i * 8]);
  }
}

// One block (192 thr) per Acat row (node prow[node0+bid]); per-thread register
// accumulation via 7-way switch; fused own-row copy into segment 0.
// Relation r accumulates in ar, divides by cnt_rel[r*Nn+v], writes segment r+1.
__global__ __launch_bounds__(192) void aggregate_kernel(
    const u16* __restrict__ H, const int* __restrict__ esrc, const int* __restrict__ etype,
    const int* __restrict__ offs, const int* __restrict__ perm, const int* __restrict__ cnt_rel,
    const int* __restrict__ prow, u16* __restrict__ Acat, int node0, int Nn) {
  int v = prow[node0 + blockIdx.x];
  int t = threadIdx.x;
  int j0 = t * 4;  // 192*4 = 768
  size_t rowbase = (size_t)blockIdx.x * KK;
  *(uint2*)&Acat[rowbase + j0] = *(const uint2*)&H[(size_t)v * DD + j0];
  float a0[4] = {0,0,0,0}, a1[4] = {0,0,0,0}, a2[4] = {0,0,0,0}, a3[4] = {0,0,0,0};
  float a4[4] = {0,0,0,0}, a5[4] = {0,0,0,0}, a6[4] = {0,0,0,0};
  int beg = offs[v], end = offs[v + 1];
  for (int e = beg; e < end; ++e) {
    int eid = perm[e];
    int src = esrc[eid];
    int rel = etype[eid] + 1;   // 0..6
    uint2 w = *(const uint2*)&H[(size_t)src * DD + j0];
    float f0 = b2f((u16)(w.x & 0xffff));
    float f1 = b2f((u16)(w.x >> 16));
    float f2 = b2f((u16)(w.y & 0xffff));
    float f3 = b2f((u16)(w.y >> 16));
    switch (rel) {
      case 0: a0[0]+=f0; a0[1]+=f1; a0[2]+=f2; a0[3]+=f3; break;
      case 1: a1[0]+=f0; a1[1]+=f1; a1[2]+=f2; a1[3]+=f3; break;
      case 2: a2[0]+=f0; a2[1]+=f1; a2[2]+=f2; a2[3]+=f3; break;
      case 3: a3[0]+=f0; a3[1]+=f1; a3[2]+=f2; a3[3]+=f3; break;
      case 4: a4[0]+=f0; a4[1]+=f1; a4[2]+=f2; a4[3]+=f3; break;
      case 5: a5[0]+=f0; a5[1]+=f1; a5[2]+=f2; a5[3]+=f3; break;
      default: a6[0]+=f0; a6[1]+=f1; a6[2]+=f2; a6[3]+=f3; break;
    }
  }
  const float* regs[NREL] = {a0, a1, a2, a3, a4, a5, a6};
#pragma unroll
  for (int r = 0; r < NREL; ++r) {
    int c = cnt_rel[(size_t)r * Nn + v];
    float inv = (c > 0) ? 1.f / (float)c : 0.f;
    const float* a = regs[r];
    u32 lo = (u32)f2bf(a[0] * inv) | ((u32)f2bf(a[1] * inv) << 16);
    u32 hi = (u32)f2bf(a[2] * inv) | ((u32)f2bf(a[3] * inv) << 16);
    uint2 o; o.x = lo; o.y = hi;
    *(uint2*)&Acat[rowbase + (size_t)(r + 1) * DD + j0] = o;
  }
}

// ---------- 256x256 8-wave GEMM with per-tile K-segment skip.
// Inner schedule = round-5 structure (best measured): BK=64, 2 LDS slots,
// 4 quadrant phases, stage A(next) in P0 / B(next) in P1, vmcnt(0) at P3.
// K-loop walks only the tile's present segments (packed u64 list).

#define MFMA_(a_, b_, c_) __builtin_amdgcn_mfma_f32_16x16x32_bf16(a_, b_, c_, 0, 0, 0)
#define BAR   __builtin_amdgcn_s_barrier()
#define SB    __builtin_amdgcn_sched_barrier(0)
#define LGKM0 asm volatile("s_waitcnt lgkmcnt(0)" ::: "memory")
#define VM0   asm volatile("s_waitcnt vmcnt(0)" ::: "memory")

__global__ __launch_bounds__(512, 2) void gemmsk_kernel(
    const u16* __restrict__ A, const u16* __restrict__ Bt, const float* __restrict__ bias,
    const int* __restrict__ prowL, const u64* __restrict__ packs, const int* __restrict__ pcnts,
    u16* __restrict__ Hout, float* __restrict__ Cout, int Mvalid, int Mtiles, int tile0) {
  __shared__ u16 sm[2][2][16384];  // [slot][A/B][16KB], row = 128 B (64 bf16)

  int tid = threadIdx.x;
  int lane = tid & 63;
  int wv = tid >> 6;
  int wm = wv >> 2, wn = wv & 3;

  // XCD-bijective block swizzle (m204), bn fastest
  int nwg = Mtiles * 3;
  int orig = (int)blockIdx.x;
  int q8 = nwg >> 3, r8 = nwg & 7;
  int xcd = orig & 7, rank = orig >> 3;
  int wg = (xcd < r8 ? xcd * (q8 + 1) : r8 * (q8 + 1) + (xcd - r8) * q8) + rank;
  int bm = wg / 3, bn = wg % 3;

  u64 pack = packs[tile0 + bm];
  int nseg = pcnts[tile0 + bm];

  // staging: linear LDS dest, inverse-swizzled global source (rule #21)
  int srow = tid >> 3;
  int sc = (tid & 7) ^ (srow & 7);
  const char* gA0 = (const char*)A  + (size_t)(bm * 256 + srow) * (KK * 2) + sc * 16;
  const char* gB0 = (const char*)Bt + (size_t)(bn * 256 + srow) * (KK * 2) + sc * 16;
  const size_t JSTRIDE = (size_t)64 * KK * 2;  // 64 rows

  // swizzled ds_read lane offsets
  int rsel = lane & 15, kq = lane >> 4;
  int off0 = rsel * 128 + (((kq)     ^ (rsel & 7)) * 16);
  int off1 = rsel * 128 + (((kq + 4) ^ (rsel & 7)) * 16);

  f32x4 acc[8][4];
#pragma unroll
  for (int m = 0; m < 8; ++m)
#pragma unroll
    for (int n = 0; n < 4; ++n) acc[m][n] = (f32x4){0.f, 0.f, 0.f, 0.f};

  int kbC = (int)(pack & 7ULL) * 12; pack >>= 8;   // segment s base (K-block units)
  int kbN = (int)(pack & 7ULL) * 12; pack >>= 8;   // segment s+1 base

  // prologue: stage tile kbC+0 into slot 0
  {
    size_t ko = (size_t)kbC * 128;
#pragma unroll
    for (int j = 0; j < 4; ++j)
      gload16(gA0 + (size_t)j * JSTRIDE + ko, (char*)&sm[0][0][0] + j * 8192 + tid * 16);
#pragma unroll
    for (int j = 0; j < 4; ++j)
      gload16(gB0 + (size_t)j * JSTRIDE + ko, (char*)&sm[0][1][0] + j * 8192 + tid * 16);
  }
  VM0;
  BAR;
  SB;

  for (int s = 0; s < nseg; ++s) {
#pragma unroll
    for (int kt = 0; kt < 12; ++kt) {
      int slot = kt & 1;
      int kbn_ = (kt < 11) ? (kbC + kt + 1) : kbN;
      int more = (s * 12 + kt) < (nseg * 12 - 1);
      size_t ko = (size_t)kbn_ * 128;
      const char* aB = (const char*)&sm[slot][0][0];
      const char* bB = (const char*)&sm[slot][1][0];
      char* aN = (char*)&sm[slot ^ 1][0][0];
      char* bN = (char*)&sm[slot ^ 1][1][0];
      short8 a03[4][2], a47[4][2], bb[2][2];

      // ---- P0: read a03(8)+b01(4); stage A(next); MFMA Q0 ----
#pragma unroll
      for (int m = 0; m < 4; ++m) {
        a03[m][0] = *(const short8*)(aB + (wm * 128 + m * 16) * 128 + off0);
        a03[m][1] = *(const short8*)(aB + (wm * 128 + m * 16) * 128 + off1);
      }
#pragma unroll
      for (int n = 0; n < 2; ++n) {
        bb[n][0] = *(const short8*)(bB + (wn * 64 + n * 16) * 128 + off0);
        bb[n][1] = *(const short8*)(bB + (wn * 64 + n * 16) * 128 + off1);
      }
      if (more) {
#pragma unroll
        for (int j = 0; j < 4; ++j)
          gload16(gA0 + (size_t)j * JSTRIDE + ko, aN + j * 8192 + tid * 16);
      }
      asm volatile("s_waitcnt lgkmcnt(8)" ::: "memory");
      SB; BAR; LGKM0; SB;
      __builtin_amdgcn_s_setprio(1);
#pragma unroll
      for (int m = 0; m < 4; ++m)
#pragma unroll
        for (int n = 0; n < 2; ++n) {
          acc[m][n] = MFMA_(a03[m][0], bb[n][0], acc[m][n]);
          acc[m][n] = MFMA_(a03[m][1], bb[n][1], acc[m][n]);
        }
      __builtin_amdgcn_s_setprio(0);
      SB; BAR;

      // ---- P1: read a47(8); stage B(next); MFMA Q1 ----
#pragma unroll
      for (int m = 0; m < 4; ++m) {
        a47[m][0] = *(const short8*)(aB + (wm * 128 + (m + 4) * 16) * 128 + off0);
        a47[m][1] = *(const short8*)(aB + (wm * 128 + (m + 4) * 16) * 128 + off1);
      }
      if (more) {
#pragma unroll
        for (int j = 0; j < 4; ++j)
          gload16(gB0 + (size_t)j * JSTRIDE + ko, bN + j * 8192 + tid * 16);
      }
      SB; BAR; LGKM0; SB;
      __builtin_amdgcn_s_setprio(1);
#pragma unroll
      for (int m = 0; m < 4; ++m)
#pragma unroll
        for (int n = 0; n < 2; ++n) {
          acc[m + 4][n] = MFMA_(a47[m][0], bb[n][0], acc[m + 4][n]);
          acc[m + 4][n] = MFMA_(a47[m][1], bb[n][1], acc[m + 4][n]);
        }
      __builtin_amdgcn_s_setprio(0);
      SB; BAR;

      // ---- P2: read b23(4); MFMA Q2 ----
#pragma unroll
      for (int n = 0; n < 2; ++n) {
        bb[n][0] = *(const short8*)(bB + (wn * 64 + (n + 2) * 16) * 128 + off0);
        bb[n][1] = *(const short8*)(bB + (wn * 64 + (n + 2) * 16) * 128 + off1);
      }
      SB; BAR; LGKM0; SB;
      __builtin_amdgcn_s_setprio(1);
#pragma unroll
      for (int m = 0; m < 4; ++m)
#pragma unroll
        for (int n = 0; n < 2; ++n) {
          acc[m + 4][n + 2] = MFMA_(a47[m][0], bb[n][0], acc[m + 4][n + 2]);
          acc[m + 4][n + 2] = MFMA_(a47[m][1], bb[n][1], acc[m + 4][n + 2]);
        }
      __builtin_amdgcn_s_setprio(0);
      SB; BAR;

      // ---- P3: MFMA Q3; vmcnt(0); barrier ----
      __builtin_amdgcn_s_setprio(1);
#pragma unroll
      for (int m = 0; m < 4; ++m)
#pragma unroll
        for (int n = 0; n < 2; ++n) {
          acc[m][n + 2] = MFMA_(a03[m][0], bb[n][0], acc[m][n + 2]);
          acc[m][n + 2] = MFMA_(a03[m][1], bb[n][1], acc[m][n + 2]);
        }
      __builtin_amdgcn_s_setprio(0);
      VM0; BAR; SB;
    }
    kbC = kbN;
    kbN = (int)(pack & 7ULL) * 12; pack >>= 8;
  }

  // ---- epilogue: bias + ReLU, scatter rows via prow ----
  int rif = (lane >> 4) * 4;
  int cidx = lane & 15;
#pragma unroll
  for (int m = 0; m < 8; ++m) {
    int rl = bm * 256 + wm * 128 + m * 16 + rif;
#pragma unroll
    for (int n = 0; n < 4; ++n) {
      int c = bn * 256 + wn * 64 + n * 16 + cidx;
      float bv = bias[c];
#pragma unroll
      for (int j = 0; j < 4; ++j) {
        int r = rl + j;
        if (r < Mvalid) {
          int nd = prowL[r];
          float v = acc[m][n][j] + bv;
          v = v > 0.f ? v : 0.f;
          if (Hout) Hout[(size_t)nd * DD + c] = f2bf(v);
          if (Cout) Cout[(size_t)nd * DD + c] = v;
        }
      }
    }
  }
}

// ---------- host ----------

static inline size_t alignup(size_t x, size_t a) { return (x + a - 1) & ~(a - 1); }

extern "C" void kernel_launch(void* const* d_in, const int* in_sizes, int n_in,
                              void* d_out, int out_size, void* d_ws, size_t ws_size,
                              hipStream_t stream) {
  const float* x       = (const float*)d_in[0];
  const int*   eidx    = (const int*)d_in[1];
  const int*   etype   = (const int*)d_in[2];
  const float* weights = (const float*)d_in[3];
  const float* roots   = (const float*)d_in[4];
  const float* biases  = (const float*)d_in[5];
  float* out = (float*)d_out;

  const int Nn = in_sizes[0] / DD;  // 20000
  const int E  = in_sizes[2];       // 100000
  const int Mpad = ((Nn + 255) / 256) * 256;
  const int Ntiles = Mpad / 256;

  char* p = (char*)d_ws;
  size_t off = 0;
  auto carve = [&](size_t bytes) -> char* {
    char* r = p + off;
    off = alignup(off + bytes, 256);
    return r;
  };
  u16* H0      = (u16*)carve((size_t)Nn * DD * 2);
  u16* Bt      = (u16*)carve((size_t)DD * KK * 2);
  int* cnt_rel = (int*)carve((size_t)NREL * Nn * 4);
  int* cnt_dst = (int*)carve((size_t)Nn * 4);
  int* offs    = (int*)carve((size_t)(Nn + 1) * 4);
  int* fill    = (int*)carve((size_t)Nn * 4);
  int* perm    = (int*)carve((size_t)E * 4);
  int* mask    = (int*)carve((size_t)Nn * 4);
  int* mh      = (int*)carve(128 * 4);
  int* mb      = (int*)carve(128 * 4);
  int* mf      = (int*)carve(128 * 4);
  int* prow    = (int*)carve((size_t)Mpad * 4);
  u64* packs   = (u64*)carve((size_t)Ntiles * 8);
  int* pcnts   = (int*)carve((size_t)Ntiles * 4);

  size_t rem = (ws_size > off) ? (ws_size - off) : 0;
  int McCap = (int)(rem / ((size_t)KK * 2));
  int Mc = (McCap < Mpad) ? (McCap & ~255) : Mpad;
  if (Mc < 256) return;  // workspace too small — fail visibly rather than corrupt
  u16* Acat = (u16*)(p + off);
  int nchunks = (Nn + Mc - 1) / Mc;
  u16* H1 = (u16*)d_out;  // bf16 ping buffer inside d_out

  (void)hipMemsetAsync(cnt_rel, 0, (size_t)NREL * Nn * 4, stream);
  (void)hipMemsetAsync(cnt_dst, 0, (size_t)Nn * 4, stream);
  (void)hipMemsetAsync(fill, 0, (size_t)Nn * 4, stream);
  (void)hipMemsetAsync(mh, 0, 128 * 4, stream);
  (void)hipMemsetAsync(mf, 0, 128 * 4, stream);

  int eg = (E + 255) / 256;
  int ng = (Nn + 255) / 256;
  count_kernel<<<eg, 256, 0, stream>>>(eidx, etype, cnt_dst, cnt_rel, E, Nn);
  scan_kernel<<<1, 1024, 0, stream>>>(cnt_dst, offs, Nn);
  fillperm_kernel<<<eg, 256, 0, stream>>>(eidx, offs, fill, perm, E);
  nodemask_kernel<<<ng, 256, 0, stream>>>(cnt_rel, mask, mh, Nn);
  mscan_kernel<<<1, 128, 0, stream>>>(mh, mb);
  mscatter_kernel<<<ng, 256, 0, stream>>>(mask, mb, mf, prow, Nn);
  tilemask_kernel<<<Ntiles, 256, 0, stream>>>(prow, mask, packs, pcnts, Nn);
  cast_x_kernel<<<2048, 256, 0, stream>>>(x, H0, (size_t)Nn * DD);

  const u16* Hin = H0;
  u16* Hnext = H1;
  for (int l = 0; l < NLAYERS; ++l) {
    wcat_kernel<<<8 * 576, 256, 0, stream>>>(weights + (size_t)l * NREL * DD * DD,
                                             roots + (size_t)l * DD * DD, Bt);
    for (int c = 0; c < nchunks; ++c) {
      int node0 = c * Mc;
      int nn = (Nn - node0 < Mc) ? (Nn - node0) : Mc;
      aggregate_kernel<<<nn, 192, 0, stream>>>(Hin, eidx, etype, offs, perm, cnt_rel,
                                               prow, Acat, node0, Nn);
      int mt = (nn + 255) / 256;
      u16* ho = (l < NLAYERS - 1) ? Hnext : nullptr;
      float* co = (l == NLAYERS - 1) ? out : nullptr;
      gemmsk_kernel<<<mt * 3, 512, 0, stream>>>(Acat, Bt, biases + (size_t)l * DD,
                                                prow + node0, packs, pcnts,
                                                ho, co, nn, mt, node0 / 256);
    }
    const u16* t_ = Hin;
    Hin = Hnext;
    Hnext = (u16*)t_;
  }
}